// Round 4
// baseline (534.461 us; speedup 1.0000x reference)
//
#include <hip/hip_runtime.h>

#define NN 100000     // nodes
#define NE 3200000    // edges
#define NG 512        // graphs
#define IND 128
#define H1D 32
#define H2D 16
#define BSH 7         // log2(bucket size)
#define BN  128       // nodes per bucket
#define NB  782       // ceil(NN/BN)
#define SL  800000    // slice stride = NN * 8 features

// ---------------- workspace layout (element offsets, 4B each) ----------------
#define O_DINV   0u          // float[100352]
#define O_ROW    100352u     // int[100352]  (needs NN+1)
#define O_BCNT   200704u     // int[1024]
#define O_BSTART 201728u     // int[1024] (need NB+1=783)
#define O_BCUR   202752u     // int[1024]
#define O_GSUM   203776u     // float[512]
#define O_GCNT   204288u     // float[512] (unused)
#define O_M1     204800u     // float[3200000]  m1 = (x@W1)*dinv, 4 slices of [NN][8]
#define O_F1     3404800u    // u32 csrb (temp) THEN float feat1[NN][32]
#define O_M2     6604800u    // float[1600000]  m2 = (feat1@W2)*dinv, 2 slices of [NN][8]
#define O_CSR    8204800u    // int[3200000]    exact per-node CSR
// total = 11,404,800 elems = 45.6 MB

__global__ __launch_bounds__(256) void k_init(int* bcnt, float* gsum) {
    int i = blockIdx.x * 256 + threadIdx.x;
    if (i < 1024) bcnt[i] = 0;
    if (i < NG) gsum[i] = 0.f;
}

__global__ __launch_bounds__(256) void k_bcount(const int* __restrict__ dst,
                                                int* __restrict__ bcnt) {
    __shared__ int lc[NB];
    int t = threadIdx.x;
    for (int i = t; i < NB; i += 256) lc[i] = 0;
    __syncthreads();
    for (int e = blockIdx.x * 256 + t; e < NE; e += gridDim.x * 256)
        atomicAdd(&lc[dst[e] >> BSH], 1);
    __syncthreads();
    for (int i = t; i < NB; i += 256)
        if (lc[i]) atomicAdd(&bcnt[i], lc[i]);
}

__global__ __launch_bounds__(1024) void k_bscan(const int* __restrict__ bcnt,
                                                int* __restrict__ bstart,
                                                int* __restrict__ bcur) {
    __shared__ int s[1024];
    int t = threadIdx.x;
    int v = (t < NB) ? bcnt[t] : 0;
    s[t] = v;
    __syncthreads();
    for (int off = 1; off < 1024; off <<= 1) {
        int u = (t >= off) ? s[t - off] : 0;
        __syncthreads();
        s[t] += u;
        __syncthreads();
    }
    int excl = s[t] - v;
    if (t < NB) { bstart[t] = excl; bcur[t] = excl; }
    if (t == NB - 1) bstart[NB] = s[t];   // = NE
}

__global__ __launch_bounds__(256) void k_binfill(const int* __restrict__ src,
                                                 const int* __restrict__ dst,
                                                 int* __restrict__ bcur,
                                                 unsigned* __restrict__ csrb) {
    __shared__ int lc[NB];
    __shared__ int lbase[NB];
    int t = threadIdx.x;
    for (int i = t; i < NB; i += 256) lc[i] = 0;
    __syncthreads();
    int base = blockIdx.x << 13;
    int end = min(base + 8192, NE);
    for (int e = base + t; e < end; e += 256)
        atomicAdd(&lc[dst[e] >> BSH], 1);
    __syncthreads();
    for (int i = t; i < NB; i += 256) {
        int c = lc[i];
        lbase[i] = c ? atomicAdd(&bcur[i], c) : 0;
    }
    __syncthreads();
    for (int e = base + t; e < end; e += 256) {
        int d = dst[e];
        int b = d >> BSH;
        int p = atomicAdd(&lbase[b], 1);
        csrb[p] = (unsigned)src[e] | ((unsigned)(d & (BN - 1)) << 17);
    }
}

__global__ __launch_bounds__(256) void k_reorder(const unsigned* __restrict__ csrb,
                                                 const int* __restrict__ bstart,
                                                 int* __restrict__ rowstart,
                                                 float* __restrict__ dinv,
                                                 int* __restrict__ csr) {
    __shared__ int h[BN];
    __shared__ int cur[BN];
    int t = threadIdx.x;
    if (t < BN) h[t] = 0;
    __syncthreads();
    int b = blockIdx.x;
    int bs_ = bstart[b], be = bstart[b + 1];
    for (int i = bs_ + t; i < be; i += 256)
        atomicAdd(&h[csrb[i] >> 17], 1);
    __syncthreads();
    int deg = (t < BN) ? h[t] : 0;
    for (int off = 1; off < BN; off <<= 1) {
        int v = (t < BN && t >= off) ? h[t - off] : 0;
        __syncthreads();
        if (t < BN) h[t] += v;
        __syncthreads();
    }
    int excl = (t < BN) ? (h[t] - deg) : 0;
    if (t < BN) cur[t] = excl;
    int node = (b << BSH) + t;
    if (t < BN && node < NN) {
        rowstart[node] = bs_ + excl;
        dinv[node] = 1.0f / sqrtf((float)(deg + 1));  // +1 self-loop
    }
    if (b == NB - 1 && t == 0) rowstart[NN] = NE;
    __syncthreads();
    for (int i = bs_ + t; i < be; i += 256) {
        unsigned p = csrb[i];
        int dl = p >> 17;
        int pos = bs_ + atomicAdd(&cur[dl], 1);
        csr[pos] = (int)(p & 0x1FFFF);
    }
}

// m1 = (x @ W1) * dinv, written into 4 feature slices of [NN][8]
__global__ __launch_bounds__(256) void k_gemm1(const float* __restrict__ x,
                                               const float* __restrict__ W1,
                                               const float* __restrict__ dinv,
                                               float* __restrict__ m1) {
    __shared__ float sWt[32 * 132];   // W1^T [k][i], pad 4
    __shared__ float sX[16 * IND];
    int t = threadIdx.x;
    for (int idx = t; idx < IND * H1D; idx += 256) {
        int i = idx >> 5, k = idx & 31;
        sWt[k * 132 + i] = W1[idx];
    }
    const float4* x4 = (const float4*)(x + (size_t)blockIdx.x * 16 * IND);
    ((float4*)sX)[t] = x4[t];
    ((float4*)sX)[t + 256] = x4[t + 256];
    __syncthreads();
    int r = t >> 5, k = t & 31;
    float a0 = 0.f, a1 = 0.f;
#pragma unroll
    for (int i = 0; i < IND; i += 4) {
        float4 w = *(const float4*)&sWt[k * 132 + i];
        float4 p = *(const float4*)&sX[r * IND + i];
        float4 s = *(const float4*)&sX[(r + 8) * IND + i];
        a0 += p.x * w.x + p.y * w.y + p.z * w.z + p.w * w.w;
        a1 += s.x * w.x + s.y * w.y + s.z * w.z + s.w * w.w;
    }
    int n0 = blockIdx.x * 16 + r;
    size_t sl = (size_t)(k >> 3) * SL + (k & 7);
    m1[sl + (size_t)n0 * 8] = a0 * dinv[n0];
    m1[sl + (size_t)(n0 + 8) * 8] = a1 * dinv[n0 + 8];
}

// layer-1 aggregate over ONE 8-feature slice (3.2MB, L2-resident).
// wave per node; lane = edge slot j (0..31) x quad q (0..1)
__global__ __launch_bounds__(256) void k_agg1s(const float* __restrict__ m1s,
                                               const float* __restrict__ dinv,
                                               const int* __restrict__ rowstart,
                                               const int* __restrict__ csr,
                                               const float* __restrict__ b1s,
                                               float* __restrict__ feat1,
                                               int off) {
    int t = threadIdx.x;
    int d = (blockIdx.x * 256 + t) >> 6;
    int lane = t & 63;
    int q = lane & 1;
    int j = lane >> 1;
    int beg = rowstart[d], end = rowstart[d + 1];
    float dv = dinv[d];
    const float4* m4 = (const float4*)m1s;   // node row = 2 float4
    float4 self = m4[(size_t)d * 2 + q];
    float ax = 0.f, ay = 0.f, az = 0.f, aw = 0.f;
    for (int i = beg + j; i < end; i += 32) {
        int s = csr[i];
        float4 a = m4[(size_t)s * 2 + q];
        ax += a.x; ay += a.y; az += a.z; aw += a.w;
    }
#pragma unroll
    for (int m = 2; m <= 32; m <<= 1) {      // reduce over edge slots (bits 1..5)
        ax += __shfl_xor(ax, m); ay += __shfl_xor(ay, m);
        az += __shfl_xor(az, m); aw += __shfl_xor(aw, m);
    }
    if (j == 0) {
        float4 bq = ((const float4*)b1s)[q];
        float4 r;
        r.x = fmaxf((ax + self.x) * dv + bq.x, 0.f);
        r.y = fmaxf((ay + self.y) * dv + bq.y, 0.f);
        r.z = fmaxf((az + self.z) * dv + bq.z, 0.f);
        r.w = fmaxf((aw + self.w) * dv + bq.w, 0.f);
        *(float4*)(feat1 + (size_t)d * 32 + off + q * 4) = r;
    }
}

// m2 = (feat1 @ W2) * dinv, written into 2 feature slices of [NN][8]
__global__ __launch_bounds__(256) void k_gemm2(const float* __restrict__ feat1,
                                               const float* __restrict__ W2,
                                               const float* __restrict__ dinv,
                                               float* __restrict__ m2) {
    __shared__ float sW[H1D * H2D];
    int t = threadIdx.x;
    if (t < H1D * H2D / 4) ((float4*)sW)[t] = ((const float4*)W2)[t];
    __syncthreads();
    int idx = blockIdx.x * 256 + t;          // grid exact: NN*16/256
    int node = idx >> 4, o = idx & 15;
    const float* row = feat1 + (size_t)node * H1D;
    float a = 0.f;
#pragma unroll
    for (int i = 0; i < H1D; ++i) a += row[i] * sW[i * H2D + o];
    m2[(size_t)(o >> 3) * SL + (size_t)node * 8 + (o & 7)] = a * dinv[node];
}

// layer-2 aggregate over ONE 8-feature slice + relu + dot(W3 half) + scatter
__global__ __launch_bounds__(256) void k_agg2s(const float* __restrict__ m2s,
                                               const float* __restrict__ dinv,
                                               const int* __restrict__ rowstart,
                                               const int* __restrict__ csr,
                                               const float* __restrict__ b2s,
                                               const float* __restrict__ W3s,
                                               const int* __restrict__ batch,
                                               float* __restrict__ gsum) {
    __shared__ float bsum[4];
    __shared__ int   bg[4];
    int t = threadIdx.x;
    int d = (blockIdx.x * 256 + t) >> 6;
    int lane = t & 63;
    int q = lane & 1;
    int j = lane >> 1;
    int beg = rowstart[d], end = rowstart[d + 1];
    float dv = dinv[d];
    const float4* m4 = (const float4*)m2s;
    float4 self = m4[(size_t)d * 2 + q];
    float ax = 0.f, ay = 0.f, az = 0.f, aw = 0.f;
    for (int i = beg + j; i < end; i += 32) {
        int s = csr[i];
        float4 a = m4[(size_t)s * 2 + q];
        ax += a.x; ay += a.y; az += a.z; aw += a.w;
    }
#pragma unroll
    for (int m = 2; m <= 32; m <<= 1) {      // reduce over edge slots (bits 1..5)
        ax += __shfl_xor(ax, m); ay += __shfl_xor(ay, m);
        az += __shfl_xor(az, m); aw += __shfl_xor(aw, m);
    }
    float4 bq = ((const float4*)b2s)[q];
    float4 wq = ((const float4*)W3s)[q];
    float v0 = fmaxf((ax + self.x) * dv + bq.x, 0.f);
    float v1 = fmaxf((ay + self.y) * dv + bq.y, 0.f);
    float v2 = fmaxf((az + self.z) * dv + bq.z, 0.f);
    float v3 = fmaxf((aw + self.w) * dv + bq.w, 0.f);
    float partial = v0 * wq.x + v1 * wq.y + v2 * wq.z + v3 * wq.w;
    partial += __shfl_xor(partial, 1);       // combine the two quads
    int w = t >> 6;
    if (lane == 0) { bg[w] = batch[d]; bsum[w] = partial; }
    __syncthreads();
    if (t == 0) {
        float s = bsum[0]; int g = bg[0];
#pragma unroll
        for (int u = 1; u < 4; ++u) {
            if (bg[u] == g) s += bsum[u];
            else { atomicAdd(&gsum[g], s); g = bg[u]; s = bsum[u]; }
        }
        atomicAdd(&gsum[g], s);
    }
}

__global__ __launch_bounds__(256) void k_final(const float* __restrict__ gsum,
                                               const int* __restrict__ batch,
                                               const float* __restrict__ b3,
                                               float* __restrict__ out) {
    int g = blockIdx.x * 256 + threadIdx.x;
    if (g >= NG) return;
    int lo = 0, hi = NN;
    while (lo < hi) { int mid = (lo + hi) >> 1; if (batch[mid] < g) lo = mid + 1; else hi = mid; }
    int lo2 = lo, hi2 = NN;
    while (lo2 < hi2) { int mid = (lo2 + hi2) >> 1; if (batch[mid] < g + 1) lo2 = mid + 1; else hi2 = mid; }
    out[g] = gsum[g] / fmaxf((float)(lo2 - lo), 1.0f) + b3[0];
}

extern "C" void kernel_launch(void* const* d_in, const int* in_sizes, int n_in,
                              void* d_out, int out_size, void* d_ws, size_t ws_size,
                              hipStream_t stream) {
    const float* x     = (const float*)d_in[0];
    const int*   src   = (const int*)d_in[1];
    const int*   dst   = src + NE;
    const int*   batch = (const int*)d_in[2];
    const float* W1 = (const float*)d_in[3];
    const float* b1 = (const float*)d_in[4];
    const float* W2 = (const float*)d_in[5];
    const float* b2 = (const float*)d_in[6];
    const float* W3 = (const float*)d_in[7];
    const float* b3 = (const float*)d_in[8];
    float* out = (float*)d_out;

    float* ws = (float*)d_ws;
    float*    dinv     = ws + O_DINV;
    int*      rowstart = (int*)(ws + O_ROW);
    int*      bcnt     = (int*)(ws + O_BCNT);
    int*      bstart   = (int*)(ws + O_BSTART);
    int*      bcur     = (int*)(ws + O_BCUR);
    float*    gsum     = ws + O_GSUM;
    float*    m1       = ws + O_M1;
    unsigned* csrb     = (unsigned*)(ws + O_F1);   // temp, dead before feat1
    float*    feat1    = ws + O_F1;
    float*    m2       = ws + O_M2;
    int*      csr      = (int*)(ws + O_CSR);

    k_init   <<<4, 256, 0, stream>>>(bcnt, gsum);
    k_bcount <<<512, 256, 0, stream>>>(dst, bcnt);
    k_bscan  <<<1, 1024, 0, stream>>>(bcnt, bstart, bcur);
    k_binfill<<<(NE + 8191) / 8192, 256, 0, stream>>>(src, dst, bcur, csrb);
    k_reorder<<<NB, 256, 0, stream>>>(csrb, bstart, rowstart, dinv, csr);

    k_gemm1  <<<NN / 16, 256, 0, stream>>>(x, W1, dinv, m1);
    for (int p = 0; p < 4; ++p)
        k_agg1s<<<NN / 4, 256, 0, stream>>>(m1 + (size_t)p * SL, dinv, rowstart, csr,
                                            b1 + 8 * p, feat1, 8 * p);
    k_gemm2  <<<NN * H2D / 256, 256, 0, stream>>>(feat1, W2, dinv, m2);
    for (int p = 0; p < 2; ++p)
        k_agg2s<<<NN / 4, 256, 0, stream>>>(m2 + (size_t)p * SL, dinv, rowstart, csr,
                                            b2 + 8 * p, W3 + 8 * p, batch, gsum);
    k_final  <<<2, 256, 0, stream>>>(gsum, batch, b3, out);
}

// Round 5
// 337.129 us; speedup vs baseline: 1.5853x; 1.5853x over previous
//
#include <hip/hip_runtime.h>
#include <hip/hip_fp16.h>

#define NN 100000     // nodes
#define NE 3200000    // edges
#define NG 512        // graphs
#define IND 128
#define H1D 32
#define H2D 16
#define BSH 7         // log2(bucket size)
#define BN  128       // nodes per bucket
#define NB  782       // ceil(NN/BN)

// ---------------- workspace layout (element offsets, 4B each) ----------------
#define O_DINV   0u          // float[100352]
#define O_ROW    100352u     // int[100352]  (needs NN+1)
#define O_BCNT   200704u     // int[1024]
#define O_BSTART 201728u     // int[1024]
#define O_BCUR   202752u     // int[1024]
#define O_GSUM   203776u     // float[512]
#define O_M1H    204800u     // __half[3200000] = m1 fp16 [NN][32], 64B rows
#define O_M2H    1804800u    // __half[1600000] = m2 fp16 [NN][16], 32B rows
#define O_CSRB   2604800u    // u32[3200000] binned (temp)
#define O_CSR    5804800u    // int[3200000] exact per-node CSR
// total = 9,004,800 elems = 36.0 MB

__global__ __launch_bounds__(256) void k_init(int* bcnt, float* gsum) {
    int i = blockIdx.x * 256 + threadIdx.x;
    if (i < 1024) bcnt[i] = 0;
    if (i < NG) gsum[i] = 0.f;
}

__global__ __launch_bounds__(256) void k_bcount(const int* __restrict__ dst,
                                                int* __restrict__ bcnt) {
    __shared__ int lc[NB];
    int t = threadIdx.x;
    for (int i = t; i < NB; i += 256) lc[i] = 0;
    __syncthreads();
    for (int e = blockIdx.x * 256 + t; e < NE; e += gridDim.x * 256)
        atomicAdd(&lc[dst[e] >> BSH], 1);
    __syncthreads();
    for (int i = t; i < NB; i += 256)
        if (lc[i]) atomicAdd(&bcnt[i], lc[i]);
}

__global__ __launch_bounds__(1024) void k_bscan(const int* __restrict__ bcnt,
                                                int* __restrict__ bstart,
                                                int* __restrict__ bcur) {
    __shared__ int s[1024];
    int t = threadIdx.x;
    int v = (t < NB) ? bcnt[t] : 0;
    s[t] = v;
    __syncthreads();
    for (int off = 1; off < 1024; off <<= 1) {
        int u = (t >= off) ? s[t - off] : 0;
        __syncthreads();
        s[t] += u;
        __syncthreads();
    }
    int excl = s[t] - v;
    if (t < NB) { bstart[t] = excl; bcur[t] = excl; }
    if (t == NB - 1) bstart[NB] = s[t];   // = NE
}

__global__ __launch_bounds__(256) void k_binfill(const int* __restrict__ src,
                                                 const int* __restrict__ dst,
                                                 int* __restrict__ bcur,
                                                 unsigned* __restrict__ csrb) {
    __shared__ int lc[NB];
    __shared__ int lbase[NB];
    int t = threadIdx.x;
    for (int i = t; i < NB; i += 256) lc[i] = 0;
    __syncthreads();
    int base = blockIdx.x << 13;
    int end = min(base + 8192, NE);
    for (int e = base + t; e < end; e += 256)
        atomicAdd(&lc[dst[e] >> BSH], 1);
    __syncthreads();
    for (int i = t; i < NB; i += 256) {
        int c = lc[i];
        lbase[i] = c ? atomicAdd(&bcur[i], c) : 0;
    }
    __syncthreads();
    for (int e = base + t; e < end; e += 256) {
        int d = dst[e];
        int b = d >> BSH;
        int p = atomicAdd(&lbase[b], 1);
        csrb[p] = (unsigned)src[e] | ((unsigned)(d & (BN - 1)) << 17);
    }
}

__global__ __launch_bounds__(256) void k_reorder(const unsigned* __restrict__ csrb,
                                                 const int* __restrict__ bstart,
                                                 int* __restrict__ rowstart,
                                                 float* __restrict__ dinv,
                                                 int* __restrict__ csr) {
    __shared__ int h[BN];
    __shared__ int cur[BN];
    int t = threadIdx.x;
    if (t < BN) h[t] = 0;
    __syncthreads();
    int b = blockIdx.x;
    int bs_ = bstart[b], be = bstart[b + 1];
    for (int i = bs_ + t; i < be; i += 256)
        atomicAdd(&h[csrb[i] >> 17], 1);
    __syncthreads();
    int deg = (t < BN) ? h[t] : 0;
    for (int off = 1; off < BN; off <<= 1) {
        int v = (t < BN && t >= off) ? h[t - off] : 0;
        __syncthreads();
        if (t < BN) h[t] += v;
        __syncthreads();
    }
    int excl = (t < BN) ? (h[t] - deg) : 0;
    if (t < BN) cur[t] = excl;
    int node = (b << BSH) + t;
    if (t < BN && node < NN) {
        rowstart[node] = bs_ + excl;
        dinv[node] = 1.0f / sqrtf((float)(deg + 1));  // +1 self-loop
    }
    if (b == NB - 1 && t == 0) rowstart[NN] = NE;
    __syncthreads();
    for (int i = bs_ + t; i < be; i += 256) {
        unsigned p = csrb[i];
        int dl = p >> 17;
        int pos = bs_ + atomicAdd(&cur[dl], 1);
        csr[pos] = (int)(p & 0x1FFFF);
    }
}

// m1 = (x @ W1) * dinv, stored fp16 [NN][32] (64B rows)
__global__ __launch_bounds__(256) void k_gemm1(const float* __restrict__ x,
                                               const float* __restrict__ W1,
                                               const float* __restrict__ dinv,
                                               __half* __restrict__ m1h) {
    __shared__ float sWt[32 * 132];   // W1^T [k][i], pad 4
    __shared__ float sX[16 * IND];
    int t = threadIdx.x;
    for (int idx = t; idx < IND * H1D; idx += 256) {
        int i = idx >> 5, k = idx & 31;
        sWt[k * 132 + i] = W1[idx];
    }
    const float4* x4 = (const float4*)(x + (size_t)blockIdx.x * 16 * IND);
    ((float4*)sX)[t] = x4[t];
    ((float4*)sX)[t + 256] = x4[t + 256];
    __syncthreads();
    int r = t >> 5, k = t & 31;
    float a0 = 0.f, a1 = 0.f;
#pragma unroll
    for (int i = 0; i < IND; i += 4) {
        float4 w = *(const float4*)&sWt[k * 132 + i];
        float4 p = *(const float4*)&sX[r * IND + i];
        float4 s = *(const float4*)&sX[(r + 8) * IND + i];
        a0 += p.x * w.x + p.y * w.y + p.z * w.z + p.w * w.w;
        a1 += s.x * w.x + s.y * w.y + s.z * w.z + s.w * w.w;
    }
    int n0 = blockIdx.x * 16 + r;
    m1h[(size_t)n0 * 32 + k] = __float2half(a0 * dinv[n0]);
    m1h[(size_t)(n0 + 8) * 32 + k] = __float2half(a1 * dinv[n0 + 8]);
}

// accumulate 8 fp16 values (one float4-worth) into 8 fp32 accumulators
__device__ __forceinline__ void h8_acc(const float4& r, float* a) {
    const __half2* h = (const __half2*)&r;
    float2 f0 = __half22float2(h[0]);
    float2 f1 = __half22float2(h[1]);
    float2 f2 = __half22float2(h[2]);
    float2 f3 = __half22float2(h[3]);
    a[0] += f0.x; a[1] += f0.y; a[2] += f1.x; a[3] += f1.y;
    a[4] += f2.x; a[5] += f2.y; a[6] += f3.x; a[7] += f3.y;
}

// layer-1 aggregate + relu + FUSED gemm2 -> m2h = (relu(.)@W2)*dinv, fp16
// 2 nodes/wave; lane = n(1b) x slot j(3b) x quad q(2b); 1 line/edge gathers
__global__ __launch_bounds__(256) void k_agg1(const __half* __restrict__ m1h,
                                              const float* __restrict__ dinv,
                                              const int* __restrict__ rowstart,
                                              const int* __restrict__ csr,
                                              const float* __restrict__ b1,
                                              const float* __restrict__ W2,
                                              __half* __restrict__ m2h) {
    int t = threadIdx.x;
    int lane = t & 63;
    int j = (lane >> 2) & 7;          // 8 edge slots
    int q = lane & 3;                 // 4 quads of 8 feats (16B each)
    int d = (blockIdx.x * 256 + t) >> 5;   // 2 nodes per wave
    int beg = rowstart[d], end = rowstart[d + 1];
    float dv = dinv[d];
    const float4* m4 = (const float4*)m1h;     // row = 4 granules of 16B
    float4 selfr = m4[(size_t)d * 4 + q];
    float a[8] = {0.f, 0.f, 0.f, 0.f, 0.f, 0.f, 0.f, 0.f};
    int i = beg + j;
    for (; i + 8 < end; i += 16) {    // 2 gathers in flight
        int s0 = csr[i], s1 = csr[i + 8];
        float4 A = m4[(size_t)s0 * 4 + q];
        float4 B = m4[(size_t)s1 * 4 + q];
        h8_acc(A, a);
        h8_acc(B, a);
    }
    if (i < end) {
        int s0 = csr[i];
        float4 A = m4[(size_t)s0 * 4 + q];
        h8_acc(A, a);
    }
#pragma unroll
    for (int m = 4; m <= 16; m <<= 1) {       // reduce over j (bits 2..4)
#pragma unroll
        for (int e = 0; e < 8; ++e) a[e] += __shfl_xor(a[e], m);
    }
    float sf[8] = {0.f, 0.f, 0.f, 0.f, 0.f, 0.f, 0.f, 0.f};
    h8_acc(selfr, sf);
    float4 ba = ((const float4*)b1)[q * 2];
    float4 bb = ((const float4*)b1)[q * 2 + 1];
    float bias[8] = {ba.x, ba.y, ba.z, ba.w, bb.x, bb.y, bb.z, bb.w};
    float v[8];
#pragma unroll
    for (int e = 0; e < 8; ++e)
        v[e] = fmaxf((a[e] + sf[e]) * dv + bias[e], 0.f);
    // fused 32x16 matvec: lane (q,j) -> outputs 2j, 2j+1 over feats q*8..q*8+7
    const float2* W2_2 = (const float2*)W2;   // [f][o]: pair idx = f*8 + j
    float p0 = 0.f, p1 = 0.f;
#pragma unroll
    for (int e = 0; e < 8; ++e) {
        float2 w = W2_2[(q * 8 + e) * 8 + j];
        p0 += v[e] * w.x;
        p1 += v[e] * w.y;
    }
    p0 += __shfl_xor(p0, 1); p1 += __shfl_xor(p1, 1);
    p0 += __shfl_xor(p0, 2); p1 += __shfl_xor(p1, 2);
    if (q == 0)
        *(__half2*)&m2h[(size_t)d * 16 + 2 * j] = __floats2half2_rn(p0 * dv, p1 * dv);
}

// layer-2 aggregate + bias + relu + dot(W3) + block-combined graph scatter
// 2 nodes/wave; lane = n(1b) x slot j(4b) x quad q(1b); 1 line/edge
__global__ __launch_bounds__(256) void k_agg2(const __half* __restrict__ m2h,
                                              const float* __restrict__ dinv,
                                              const int* __restrict__ rowstart,
                                              const int* __restrict__ csr,
                                              const float* __restrict__ b2,
                                              const float* __restrict__ W3,
                                              const int* __restrict__ batch,
                                              float* __restrict__ gsum) {
    __shared__ float bsum[8];
    __shared__ int   bg[8];
    int t = threadIdx.x;
    int lane = t & 63;
    int j = (lane >> 1) & 15;         // 16 edge slots
    int q = lane & 1;                 // 2 halves of 8 feats (16B each)
    int d = (blockIdx.x * 256 + t) >> 5;   // 2 nodes per wave
    int beg = rowstart[d], end = rowstart[d + 1];
    float dv = dinv[d];
    const float4* m4 = (const float4*)m2h;     // row = 2 granules of 16B
    float4 selfr = m4[(size_t)d * 2 + q];
    float a[8] = {0.f, 0.f, 0.f, 0.f, 0.f, 0.f, 0.f, 0.f};
    int i = beg + j;
    for (; i + 16 < end; i += 32) {
        int s0 = csr[i], s1 = csr[i + 16];
        float4 A = m4[(size_t)s0 * 2 + q];
        float4 B = m4[(size_t)s1 * 2 + q];
        h8_acc(A, a);
        h8_acc(B, a);
    }
    if (i < end) {
        int s0 = csr[i];
        float4 A = m4[(size_t)s0 * 2 + q];
        h8_acc(A, a);
    }
#pragma unroll
    for (int m = 2; m <= 16; m <<= 1) {       // reduce over j (bits 1..4)
#pragma unroll
        for (int e = 0; e < 8; ++e) a[e] += __shfl_xor(a[e], m);
    }
    float sf[8] = {0.f, 0.f, 0.f, 0.f, 0.f, 0.f, 0.f, 0.f};
    h8_acc(selfr, sf);
    float4 ba = ((const float4*)b2)[q * 2];
    float4 bb = ((const float4*)b2)[q * 2 + 1];
    float4 wa = ((const float4*)W3)[q * 2];
    float4 wb = ((const float4*)W3)[q * 2 + 1];
    float bias[8] = {ba.x, ba.y, ba.z, ba.w, bb.x, bb.y, bb.z, bb.w};
    float w3[8]   = {wa.x, wa.y, wa.z, wa.w, wb.x, wb.y, wb.z, wb.w};
    float partial = 0.f;
#pragma unroll
    for (int e = 0; e < 8; ++e) {
        float v = fmaxf((a[e] + sf[e]) * dv + bias[e], 0.f);
        partial += v * w3[e];
    }
    partial += __shfl_xor(partial, 1);        // combine the two quads
    int hw = t >> 5;                          // half-wave index in block (0..7)
    if ((lane & 31) == 0) { bg[hw] = batch[d]; bsum[hw] = partial; }
    __syncthreads();
    if (t == 0) {      // combine the block's 8 nodes (batch sorted)
        float s = bsum[0]; int g = bg[0];
#pragma unroll
        for (int u = 1; u < 8; ++u) {
            if (bg[u] == g) s += bsum[u];
            else { atomicAdd(&gsum[g], s); g = bg[u]; s = bsum[u]; }
        }
        atomicAdd(&gsum[g], s);
    }
}

__global__ __launch_bounds__(256) void k_final(const float* __restrict__ gsum,
                                               const int* __restrict__ batch,
                                               const float* __restrict__ b3,
                                               float* __restrict__ out) {
    int g = blockIdx.x * 256 + threadIdx.x;
    if (g >= NG) return;
    int lo = 0, hi = NN;
    while (lo < hi) { int mid = (lo + hi) >> 1; if (batch[mid] < g) lo = mid + 1; else hi = mid; }
    int lo2 = lo, hi2 = NN;
    while (lo2 < hi2) { int mid = (lo2 + hi2) >> 1; if (batch[mid] < g + 1) lo2 = mid + 1; else hi2 = mid; }
    out[g] = gsum[g] / fmaxf((float)(lo2 - lo), 1.0f) + b3[0];
}

extern "C" void kernel_launch(void* const* d_in, const int* in_sizes, int n_in,
                              void* d_out, int out_size, void* d_ws, size_t ws_size,
                              hipStream_t stream) {
    const float* x     = (const float*)d_in[0];
    const int*   src   = (const int*)d_in[1];
    const int*   dst   = src + NE;
    const int*   batch = (const int*)d_in[2];
    const float* W1 = (const float*)d_in[3];
    const float* b1 = (const float*)d_in[4];
    const float* W2 = (const float*)d_in[5];
    const float* b2 = (const float*)d_in[6];
    const float* W3 = (const float*)d_in[7];
    const float* b3 = (const float*)d_in[8];
    float* out = (float*)d_out;

    float* ws = (float*)d_ws;
    float*    dinv     = ws + O_DINV;
    int*      rowstart = (int*)(ws + O_ROW);
    int*      bcnt     = (int*)(ws + O_BCNT);
    int*      bstart   = (int*)(ws + O_BSTART);
    int*      bcur     = (int*)(ws + O_BCUR);
    float*    gsum     = ws + O_GSUM;
    __half*   m1h      = (__half*)(ws + O_M1H);
    __half*   m2h      = (__half*)(ws + O_M2H);
    unsigned* csrb     = (unsigned*)(ws + O_CSRB);
    int*      csr      = (int*)(ws + O_CSR);

    k_init   <<<4, 256, 0, stream>>>(bcnt, gsum);
    k_bcount <<<512, 256, 0, stream>>>(dst, bcnt);
    k_bscan  <<<1, 1024, 0, stream>>>(bcnt, bstart, bcur);
    k_binfill<<<(NE + 8191) / 8192, 256, 0, stream>>>(src, dst, bcur, csrb);
    k_reorder<<<NB, 256, 0, stream>>>(csrb, bstart, rowstart, dinv, csr);

    k_gemm1  <<<NN / 16, 256, 0, stream>>>(x, W1, dinv, m1h);
    k_agg1   <<<NN / 8, 256, 0, stream>>>(m1h, dinv, rowstart, csr, b1, W2, m2h);
    k_agg2   <<<NN / 8, 256, 0, stream>>>(m2h, dinv, rowstart, csr, b2, W3, batch, gsum);
    k_final  <<<2, 256, 0, stream>>>(gsum, batch, b3, out);
}

// Round 6
// 322.447 us; speedup vs baseline: 1.6575x; 1.0455x over previous
//
#include <hip/hip_runtime.h>
#include <hip/hip_fp16.h>

#define NN 100000     // nodes
#define NE 3200000    // edges
#define NG 512        // graphs
#define IND 128
#define H1D 32
#define H2D 16
#define BSH 7         // log2(bucket size)
#define BN  128       // nodes per bucket
#define NB  782       // ceil(NN/BN)
#define TILE 16384    // edges per binfill block (longer runs -> full-line writes)

// ---------------- workspace layout (element offsets, 4B each) ----------------
#define O_DINV   0u          // float[100352]
#define O_ROW    100352u     // int[100352]  (needs NN+1)
#define O_BCNT   200704u     // int[1024]
#define O_BSTART 201728u     // int[1024]
#define O_BCUR   202752u     // int[1024]
#define O_GSUM   203776u     // float[512]
#define O_M1H    204800u     // __half[3200000] = m1 fp16 [NN][32], 64B rows
#define O_M2H    1804800u    // __half[1600000] = m2 fp16 [NN][16], 32B rows
#define O_CSRB   2604800u    // u32[3200000] binned (temp)
#define O_CSR    5804800u    // int[3200000] exact per-node CSR
// total = 9,004,800 elems = 36.0 MB

__global__ __launch_bounds__(256) void k_init(int* bcnt, float* gsum) {
    int i = blockIdx.x * 256 + threadIdx.x;
    if (i < 1024) bcnt[i] = 0;
    if (i < NG) gsum[i] = 0.f;
}

__global__ __launch_bounds__(256) void k_bcount(const int* __restrict__ dst,
                                                int* __restrict__ bcnt) {
    __shared__ int lc[NB];
    int t = threadIdx.x;
    for (int i = t; i < NB; i += 256) lc[i] = 0;
    __syncthreads();
    const int4* d4 = (const int4*)dst;
    for (int e = blockIdx.x * 256 + t; e < NE / 4; e += gridDim.x * 256) {
        int4 v = d4[e];
        atomicAdd(&lc[v.x >> BSH], 1);
        atomicAdd(&lc[v.y >> BSH], 1);
        atomicAdd(&lc[v.z >> BSH], 1);
        atomicAdd(&lc[v.w >> BSH], 1);
    }
    __syncthreads();
    for (int i = t; i < NB; i += 256)
        if (lc[i]) atomicAdd(&bcnt[i], lc[i]);
}

__global__ __launch_bounds__(1024) void k_bscan(const int* __restrict__ bcnt,
                                                int* __restrict__ bstart,
                                                int* __restrict__ bcur) {
    __shared__ int s[1024];
    int t = threadIdx.x;
    int v = (t < NB) ? bcnt[t] : 0;
    s[t] = v;
    __syncthreads();
    for (int off = 1; off < 1024; off <<= 1) {
        int u = (t >= off) ? s[t - off] : 0;
        __syncthreads();
        s[t] += u;
        __syncthreads();
    }
    int excl = s[t] - v;
    if (t < NB) { bstart[t] = excl; bcur[t] = excl; }
    if (t == NB - 1) bstart[NB] = s[t];   // = NE
}

// binned fill, 16K-edge tiles: LDS count -> per-bucket bump alloc -> place.
// Runs of ~21 edges (84B) per (tile,bucket) -> mostly full-line HBM writes.
__global__ __launch_bounds__(256) void k_binfill(const int* __restrict__ src,
                                                 const int* __restrict__ dst,
                                                 int* __restrict__ bcur,
                                                 unsigned* __restrict__ csrb) {
    __shared__ int lc[NB];
    __shared__ int lbase[NB];
    int t = threadIdx.x;
    for (int i = t; i < NB; i += 256) lc[i] = 0;
    __syncthreads();
    int base = blockIdx.x * TILE;
    int end = min(base + TILE, NE);
    int n4 = (end - base) >> 2;           // NE and TILE are multiples of 4
    const int4* dst4 = (const int4*)(dst + base);
    const int4* src4 = (const int4*)(src + base);
    for (int u = t; u < n4; u += 256) {
        int4 v = dst4[u];
        atomicAdd(&lc[v.x >> BSH], 1);
        atomicAdd(&lc[v.y >> BSH], 1);
        atomicAdd(&lc[v.z >> BSH], 1);
        atomicAdd(&lc[v.w >> BSH], 1);
    }
    __syncthreads();
    for (int i = t; i < NB; i += 256) {
        int c = lc[i];
        lbase[i] = c ? atomicAdd(&bcur[i], c) : 0;
    }
    __syncthreads();
    for (int u = t; u < n4; u += 256) {
        int4 vd = dst4[u];
        int4 vs = src4[u];
        int b0 = vd.x >> BSH, p0 = atomicAdd(&lbase[b0], 1);
        csrb[p0] = (unsigned)vs.x | ((unsigned)(vd.x & (BN - 1)) << 17);
        int b1 = vd.y >> BSH, p1 = atomicAdd(&lbase[b1], 1);
        csrb[p1] = (unsigned)vs.y | ((unsigned)(vd.y & (BN - 1)) << 17);
        int b2 = vd.z >> BSH, p2 = atomicAdd(&lbase[b2], 1);
        csrb[p2] = (unsigned)vs.z | ((unsigned)(vd.z & (BN - 1)) << 17);
        int b3 = vd.w >> BSH, p3 = atomicAdd(&lbase[b3], 1);
        csrb[p3] = (unsigned)vs.w | ((unsigned)(vd.w & (BN - 1)) << 17);
    }
}

__global__ __launch_bounds__(256) void k_reorder(const unsigned* __restrict__ csrb,
                                                 const int* __restrict__ bstart,
                                                 int* __restrict__ rowstart,
                                                 float* __restrict__ dinv,
                                                 int* __restrict__ csr) {
    __shared__ int h[BN];
    __shared__ int cur[BN];
    int t = threadIdx.x;
    if (t < BN) h[t] = 0;
    __syncthreads();
    int b = blockIdx.x;
    int bs_ = bstart[b], be = bstart[b + 1];
    for (int i = bs_ + t; i < be; i += 256)
        atomicAdd(&h[csrb[i] >> 17], 1);
    __syncthreads();
    int deg = (t < BN) ? h[t] : 0;
    for (int off = 1; off < BN; off <<= 1) {
        int v = (t < BN && t >= off) ? h[t - off] : 0;
        __syncthreads();
        if (t < BN) h[t] += v;
        __syncthreads();
    }
    int excl = (t < BN) ? (h[t] - deg) : 0;
    if (t < BN) cur[t] = excl;
    int node = (b << BSH) + t;
    if (t < BN && node < NN) {
        rowstart[node] = bs_ + excl;
        dinv[node] = 1.0f / sqrtf((float)(deg + 1));  // +1 self-loop
    }
    if (b == NB - 1 && t == 0) rowstart[NN] = NE;
    __syncthreads();
    for (int i = bs_ + t; i < be; i += 256) {
        unsigned p = csrb[i];
        int dl = p >> 17;
        int pos = bs_ + atomicAdd(&cur[dl], 1);
        csr[pos] = (int)(p & 0x1FFFF);
    }
}

// m1 = (x @ W1) * dinv, stored fp16 [NN][32] (64B rows)
__global__ __launch_bounds__(256) void k_gemm1(const float* __restrict__ x,
                                               const float* __restrict__ W1,
                                               const float* __restrict__ dinv,
                                               __half* __restrict__ m1h) {
    __shared__ float sWt[32 * 132];   // W1^T [k][i], pad 4
    __shared__ float sX[16 * IND];
    int t = threadIdx.x;
    for (int idx = t; idx < IND * H1D; idx += 256) {
        int i = idx >> 5, k = idx & 31;
        sWt[k * 132 + i] = W1[idx];
    }
    const float4* x4 = (const float4*)(x + (size_t)blockIdx.x * 16 * IND);
    ((float4*)sX)[t] = x4[t];
    ((float4*)sX)[t + 256] = x4[t + 256];
    __syncthreads();
    int r = t >> 5, k = t & 31;
    float a0 = 0.f, a1 = 0.f;
#pragma unroll
    for (int i = 0; i < IND; i += 4) {
        float4 w = *(const float4*)&sWt[k * 132 + i];
        float4 p = *(const float4*)&sX[r * IND + i];
        float4 s = *(const float4*)&sX[(r + 8) * IND + i];
        a0 += p.x * w.x + p.y * w.y + p.z * w.z + p.w * w.w;
        a1 += s.x * w.x + s.y * w.y + s.z * w.z + s.w * w.w;
    }
    int n0 = blockIdx.x * 16 + r;
    m1h[(size_t)n0 * 32 + k] = __float2half(a0 * dinv[n0]);
    m1h[(size_t)(n0 + 8) * 32 + k] = __float2half(a1 * dinv[n0 + 8]);
}

// accumulate 8 fp16 values (one float4-worth) into 8 fp32 accumulators
__device__ __forceinline__ void h8_acc(const float4& r, float* a) {
    const __half2* h = (const __half2*)&r;
    float2 f0 = __half22float2(h[0]);
    float2 f1 = __half22float2(h[1]);
    float2 f2 = __half22float2(h[2]);
    float2 f3 = __half22float2(h[3]);
    a[0] += f0.x; a[1] += f0.y; a[2] += f1.x; a[3] += f1.y;
    a[4] += f2.x; a[5] += f2.y; a[6] += f3.x; a[7] += f3.y;
}

// layer-1 aggregate + relu + FUSED gemm2 -> m2h = (relu(.)@W2)*dinv, fp16
// 2 nodes/wave; lane = n(1b) x slot j(3b) x quad q(2b); 4-deep gather unroll
__global__ __launch_bounds__(256) void k_agg1(const __half* __restrict__ m1h,
                                              const float* __restrict__ dinv,
                                              const int* __restrict__ rowstart,
                                              const int* __restrict__ csr,
                                              const float* __restrict__ b1,
                                              const float* __restrict__ W2,
                                              __half* __restrict__ m2h) {
    int t = threadIdx.x;
    int lane = t & 63;
    int j = (lane >> 2) & 7;          // 8 edge slots
    int q = lane & 3;                 // 4 quads of 8 feats (16B each)
    int d = (blockIdx.x * 256 + t) >> 5;   // 2 nodes per wave
    int beg = rowstart[d], end = rowstart[d + 1];
    float dv = dinv[d];
    const float4* m4 = (const float4*)m1h;     // row = 4 granules of 16B
    float4 selfr = m4[(size_t)d * 4 + q];
    float a[8] = {0.f, 0.f, 0.f, 0.f, 0.f, 0.f, 0.f, 0.f};
    int i = beg + j;
    for (; i + 24 < end; i += 32) {   // 4 gathers in flight
        int s0 = csr[i], s1 = csr[i + 8], s2 = csr[i + 16], s3 = csr[i + 24];
        float4 A = m4[(size_t)s0 * 4 + q];
        float4 B = m4[(size_t)s1 * 4 + q];
        float4 C = m4[(size_t)s2 * 4 + q];
        float4 D = m4[(size_t)s3 * 4 + q];
        h8_acc(A, a); h8_acc(B, a); h8_acc(C, a); h8_acc(D, a);
    }
    for (; i + 8 < end; i += 16) {
        int s0 = csr[i], s1 = csr[i + 8];
        float4 A = m4[(size_t)s0 * 4 + q];
        float4 B = m4[(size_t)s1 * 4 + q];
        h8_acc(A, a); h8_acc(B, a);
    }
    if (i < end) {
        int s0 = csr[i];
        float4 A = m4[(size_t)s0 * 4 + q];
        h8_acc(A, a);
    }
#pragma unroll
    for (int m = 4; m <= 16; m <<= 1) {       // reduce over j (bits 2..4)
#pragma unroll
        for (int e = 0; e < 8; ++e) a[e] += __shfl_xor(a[e], m);
    }
    float sf[8] = {0.f, 0.f, 0.f, 0.f, 0.f, 0.f, 0.f, 0.f};
    h8_acc(selfr, sf);
    float4 ba = ((const float4*)b1)[q * 2];
    float4 bb = ((const float4*)b1)[q * 2 + 1];
    float bias[8] = {ba.x, ba.y, ba.z, ba.w, bb.x, bb.y, bb.z, bb.w};
    float v[8];
#pragma unroll
    for (int e = 0; e < 8; ++e)
        v[e] = fmaxf((a[e] + sf[e]) * dv + bias[e], 0.f);
    // fused 32x16 matvec: lane (q,j) -> outputs 2j, 2j+1 over feats q*8..q*8+7
    const float2* W2_2 = (const float2*)W2;   // [f][o]: pair idx = f*8 + j
    float p0 = 0.f, p1 = 0.f;
#pragma unroll
    for (int e = 0; e < 8; ++e) {
        float2 w = W2_2[(q * 8 + e) * 8 + j];
        p0 += v[e] * w.x;
        p1 += v[e] * w.y;
    }
    p0 += __shfl_xor(p0, 1); p1 += __shfl_xor(p1, 1);
    p0 += __shfl_xor(p0, 2); p1 += __shfl_xor(p1, 2);
    if (q == 0)
        *(__half2*)&m2h[(size_t)d * 16 + 2 * j] = __floats2half2_rn(p0 * dv, p1 * dv);
}

// layer-2 aggregate + bias + relu + dot(W3) + block-combined graph scatter
// 2 nodes/wave; lane = n(1b) x slot j(4b) x quad q(1b); deep gather unroll
__global__ __launch_bounds__(256) void k_agg2(const __half* __restrict__ m2h,
                                              const float* __restrict__ dinv,
                                              const int* __restrict__ rowstart,
                                              const int* __restrict__ csr,
                                              const float* __restrict__ b2,
                                              const float* __restrict__ W3,
                                              const int* __restrict__ batch,
                                              float* __restrict__ gsum) {
    __shared__ float bsum[8];
    __shared__ int   bg[8];
    int t = threadIdx.x;
    int lane = t & 63;
    int j = (lane >> 1) & 15;         // 16 edge slots
    int q = lane & 1;                 // 2 halves of 8 feats (16B each)
    int d = (blockIdx.x * 256 + t) >> 5;   // 2 nodes per wave
    int beg = rowstart[d], end = rowstart[d + 1];
    float dv = dinv[d];
    const float4* m4 = (const float4*)m2h;     // row = 2 granules of 16B
    float4 selfr = m4[(size_t)d * 2 + q];
    float a[8] = {0.f, 0.f, 0.f, 0.f, 0.f, 0.f, 0.f, 0.f};
    int i = beg + j;
    for (; i + 48 < end; i += 64) {   // 4 gathers in flight (high-degree nodes)
        int s0 = csr[i], s1 = csr[i + 16], s2 = csr[i + 32], s3 = csr[i + 48];
        float4 A = m4[(size_t)s0 * 2 + q];
        float4 B = m4[(size_t)s1 * 2 + q];
        float4 C = m4[(size_t)s2 * 2 + q];
        float4 D = m4[(size_t)s3 * 2 + q];
        h8_acc(A, a); h8_acc(B, a); h8_acc(C, a); h8_acc(D, a);
    }
    for (; i + 16 < end; i += 32) {
        int s0 = csr[i], s1 = csr[i + 16];
        float4 A = m4[(size_t)s0 * 2 + q];
        float4 B = m4[(size_t)s1 * 2 + q];
        h8_acc(A, a); h8_acc(B, a);
    }
    if (i < end) {
        int s0 = csr[i];
        float4 A = m4[(size_t)s0 * 2 + q];
        h8_acc(A, a);
    }
#pragma unroll
    for (int m = 2; m <= 16; m <<= 1) {       // reduce over j (bits 1..4)
#pragma unroll
        for (int e = 0; e < 8; ++e) a[e] += __shfl_xor(a[e], m);
    }
    float sf[8] = {0.f, 0.f, 0.f, 0.f, 0.f, 0.f, 0.f, 0.f};
    h8_acc(selfr, sf);
    float4 ba = ((const float4*)b2)[q * 2];
    float4 bb = ((const float4*)b2)[q * 2 + 1];
    float4 wa = ((const float4*)W3)[q * 2];
    float4 wb = ((const float4*)W3)[q * 2 + 1];
    float bias[8] = {ba.x, ba.y, ba.z, ba.w, bb.x, bb.y, bb.z, bb.w};
    float w3[8]   = {wa.x, wa.y, wa.z, wa.w, wb.x, wb.y, wb.z, wb.w};
    float partial = 0.f;
#pragma unroll
    for (int e = 0; e < 8; ++e) {
        float v = fmaxf((a[e] + sf[e]) * dv + bias[e], 0.f);
        partial += v * w3[e];
    }
    partial += __shfl_xor(partial, 1);        // combine the two quads
    int hw = t >> 5;                          // half-wave index in block (0..7)
    if ((lane & 31) == 0) { bg[hw] = batch[d]; bsum[hw] = partial; }
    __syncthreads();
    if (t == 0) {      // combine the block's 8 nodes (batch sorted)
        float s = bsum[0]; int g = bg[0];
#pragma unroll
        for (int u = 1; u < 8; ++u) {
            if (bg[u] == g) s += bsum[u];
            else { atomicAdd(&gsum[g], s); g = bg[u]; s = bsum[u]; }
        }
        atomicAdd(&gsum[g], s);
    }
}

__global__ __launch_bounds__(256) void k_final(const float* __restrict__ gsum,
                                               const int* __restrict__ batch,
                                               const float* __restrict__ b3,
                                               float* __restrict__ out) {
    int g = blockIdx.x * 256 + threadIdx.x;
    if (g >= NG) return;
    int lo = 0, hi = NN;
    while (lo < hi) { int mid = (lo + hi) >> 1; if (batch[mid] < g) lo = mid + 1; else hi = mid; }
    int lo2 = lo, hi2 = NN;
    while (lo2 < hi2) { int mid = (lo2 + hi2) >> 1; if (batch[mid] < g + 1) lo2 = mid + 1; else hi2 = mid; }
    out[g] = gsum[g] / fmaxf((float)(lo2 - lo), 1.0f) + b3[0];
}

extern "C" void kernel_launch(void* const* d_in, const int* in_sizes, int n_in,
                              void* d_out, int out_size, void* d_ws, size_t ws_size,
                              hipStream_t stream) {
    const float* x     = (const float*)d_in[0];
    const int*   src   = (const int*)d_in[1];
    const int*   dst   = src + NE;
    const int*   batch = (const int*)d_in[2];
    const float* W1 = (const float*)d_in[3];
    const float* b1 = (const float*)d_in[4];
    const float* W2 = (const float*)d_in[5];
    const float* b2 = (const float*)d_in[6];
    const float* W3 = (const float*)d_in[7];
    const float* b3 = (const float*)d_in[8];
    float* out = (float*)d_out;

    float* ws = (float*)d_ws;
    float*    dinv     = ws + O_DINV;
    int*      rowstart = (int*)(ws + O_ROW);
    int*      bcnt     = (int*)(ws + O_BCNT);
    int*      bstart   = (int*)(ws + O_BSTART);
    int*      bcur     = (int*)(ws + O_BCUR);
    float*    gsum     = ws + O_GSUM;
    __half*   m1h      = (__half*)(ws + O_M1H);
    __half*   m2h      = (__half*)(ws + O_M2H);
    unsigned* csrb     = (unsigned*)(ws + O_CSRB);
    int*      csr      = (int*)(ws + O_CSR);

    k_init   <<<4, 256, 0, stream>>>(bcnt, gsum);
    k_bcount <<<512, 256, 0, stream>>>(dst, bcnt);
    k_bscan  <<<1, 1024, 0, stream>>>(bcnt, bstart, bcur);
    k_binfill<<<(NE + TILE - 1) / TILE, 256, 0, stream>>>(src, dst, bcur, csrb);
    k_reorder<<<NB, 256, 0, stream>>>(csrb, bstart, rowstart, dinv, csr);

    k_gemm1  <<<NN / 16, 256, 0, stream>>>(x, W1, dinv, m1h);
    k_agg1   <<<NN / 8, 256, 0, stream>>>(m1h, dinv, rowstart, csr, b1, W2, m2h);
    k_agg2   <<<NN / 8, 256, 0, stream>>>(m2h, dinv, rowstart, csr, b2, W3, batch, gsum);
    k_final  <<<2, 256, 0, stream>>>(gsum, batch, b3, out);
}